// Round 1
// baseline (1946.407 us; speedup 1.0000x reference)
//
#include <hip/hip_runtime.h>
#include <math.h>

#define NPTS 131072
#define DIM 32
#define MCL 256

// ---------------------------------------------------------------------------
// prep: per cluster m compute
//   Bws[m]  = L[m]^T                      (32x32)
//   bws[m]  = L[m]^T c[m]                 (32)
//   lcws[m] = log|w_m| - log(sum|w|) + log|det L[m]|
// so that q_im = || Bws[m] x_i - bws[m] ||^2  and
// ll_i = logsumexp_m( -0.5 q_im + lcws[m] ).
// det(L L^T) = det(L)^2  ->  sqrt(det(cov_inv)) = |det L|.
// ---------------------------------------------------------------------------
__global__ __launch_bounds__(64) void gmm_prep(
    const float* __restrict__ center,
    const float* __restrict__ L,
    const float* __restrict__ weight,
    float* __restrict__ Bws,   // [MCL][32][32]
    float* __restrict__ bws,   // [MCL][32]
    float* __restrict__ lcws)  // [MCL]
{
    const int m = blockIdx.x;
    const int t = threadIdx.x;
    __shared__ float mat[DIM][DIM + 1];
    __shared__ int pivsh;

    const float* Lm = L + m * DIM * DIM;
    for (int k = t; k < DIM * DIM; k += 64)
        mat[k >> 5][k & 31] = Lm[k];
    __syncthreads();

    // B = L^T
    float* Bm = Bws + m * DIM * DIM;
    for (int k = t; k < DIM * DIM; k += 64) {
        const int d = k >> 5, j = k & 31;
        Bm[k] = mat[j][d];
    }
    // b[d] = sum_j L[j][d] * c[j]
    if (t < DIM) {
        float acc = 0.f;
        for (int j = 0; j < DIM; ++j) acc += mat[j][t] * center[m * DIM + j];
        bws[m * DIM + t] = acc;
    }
    __syncthreads();

    // Gaussian elimination with partial pivoting (destroys mat) -> log|det|
    float logdet = 0.f;
    for (int k = 0; k < DIM; ++k) {
        if (t == 0) {
            int piv = k;
            float best = fabsf(mat[k][k]);
            for (int r = k + 1; r < DIM; ++r) {
                const float v = fabsf(mat[r][k]);
                if (v > best) { best = v; piv = r; }
            }
            pivsh = piv;
        }
        __syncthreads();
        const int piv = pivsh;
        if (piv != k && t < DIM) {
            const float tmp = mat[k][t];
            mat[k][t] = mat[piv][t];
            mat[piv][t] = tmp;
        }
        __syncthreads();
        const float pv = mat[k][k];
        logdet += logf(fabsf(pv));     // uniform across threads; only t==0 uses it
        if (t > k && t < DIM) {
            const float f = mat[t][k] / pv;
            for (int j = k; j < DIM; ++j) mat[t][j] -= f * mat[k][j];
        }
        __syncthreads();
    }

    if (t == 0) {
        float wsum = 0.f;
        for (int j = 0; j < MCL; ++j) wsum += fabsf(weight[j]);
        lcws[m] = logf(fabsf(weight[m])) - logf(wsum) + logdet;
    }
}

// ---------------------------------------------------------------------------
// main: one thread per point. x_i lives in 32 VGPRs; B rows are read through
// wave-uniform addresses (compiler scalarizes -> s_load feeding v_fmac SGPR
// operand, no LDS). 4 independent FMA chains hide the 4-cyc dep latency.
// Online weighted logsumexp in registers.
// ---------------------------------------------------------------------------
__global__ __launch_bounds__(256) void gmm_main(
    const float* __restrict__ X,
    const float* __restrict__ Bws,
    const float* __restrict__ bws,
    const float* __restrict__ lcws,
    const float* __restrict__ thr,
    float* __restrict__ out)
{
    const int i = blockIdx.x * 256 + threadIdx.x;
    float x[DIM];
    const float4* Xi = reinterpret_cast<const float4*>(X + (size_t)i * DIM);
    #pragma unroll
    for (int j = 0; j < 8; ++j) {
        const float4 v = Xi[j];
        x[4 * j + 0] = v.x;
        x[4 * j + 1] = v.y;
        x[4 * j + 2] = v.z;
        x[4 * j + 3] = v.w;
    }

    float mx = -INFINITY, s = 0.f;
    for (int m = 0; m < MCL; ++m) {
        const float* __restrict__ Bm = Bws + m * DIM * DIM;
        const float* __restrict__ bm = bws + m * DIM;
        float q = 0.f;
        #pragma unroll 2
        for (int d = 0; d < DIM; d += 2) {
            const float* __restrict__ r0 = Bm + d * DIM;
            const float* __restrict__ r1 = r0 + DIM;
            float a0 = 0.f, a1 = 0.f, b0 = 0.f, b1 = 0.f;
            #pragma unroll
            for (int j = 0; j < DIM; j += 2) {
                a0 = fmaf(r0[j],     x[j],     a0);
                a1 = fmaf(r0[j + 1], x[j + 1], a1);
                b0 = fmaf(r1[j],     x[j],     b0);
                b1 = fmaf(r1[j + 1], x[j + 1], b1);
            }
            const float ya = (a0 + a1) - bm[d];
            const float yb = (b0 + b1) - bm[d + 1];
            q = fmaf(ya, ya, q);
            q = fmaf(yb, yb, q);
        }
        const float dv = fmaf(q, -0.5f, lcws[m]);
        // branchless online logsumexp; first iter: mx=-inf -> exp(-inf)=0, s=1
        const float nm = fmaxf(mx, dv);
        s = fmaf(s, __expf(mx - nm), __expf(dv - nm));
        mx = nm;
    }
    out[i] = mx + logf(s) - thr[0];
}

extern "C" void kernel_launch(void* const* d_in, const int* in_sizes, int n_in,
                              void* d_out, int out_size, void* d_ws, size_t ws_size,
                              hipStream_t stream)
{
    const float* X      = (const float*)d_in[0];
    const float* center = (const float*)d_in[1];
    const float* L      = (const float*)d_in[2];
    const float* weight = (const float*)d_in[3];
    const float* thr    = (const float*)d_in[4];
    float* out = (float*)d_out;

    // ws layout: B [256*1024] f32 | b [256*32] f32 | logcoef [256] f32  (~1.08 MB)
    float* Bws  = (float*)d_ws;
    float* bws  = Bws + MCL * DIM * DIM;
    float* lcws = bws + MCL * DIM;

    gmm_prep<<<MCL, 64, 0, stream>>>(center, L, weight, Bws, bws, lcws);
    gmm_main<<<NPTS / 256, 256, 0, stream>>>(X, Bws, bws, lcws, thr, out);
}

// Round 2
// 146.086 us; speedup vs baseline: 13.3237x; 13.3237x over previous
//
#include <hip/hip_runtime.h>
#include <math.h>

#define NPTS 131072
#define DIM 32
#define MCL 256
#define KSTEPS 33          // 32 xx-steps + 1 linear (-2Ac) step
#define BPTS 256           // points per block
#define THREADS 512

typedef __attribute__((ext_vector_type(8))) short s8v;    // 8 bf16 bit-patterns
typedef __attribute__((ext_vector_type(4))) float f32x4;

__device__ __forceinline__ unsigned short f2bf(float f) {
    union { float f; unsigned u; } v; v.f = f;
    unsigned r = v.u + 0x7fffu + ((v.u >> 16) & 1u);   // RNE
    return (unsigned short)(r >> 16);
}

// ---------------------------------------------------------------------------
// prep: per cluster m (one block):
//   A = L L^T;  E = A - I  -> G rows [32j+l] in bf16, MFMA-fragment order
//   G row [1024+j] = -2*(A c)[j]
//   cst[m] = log|w_m| - log(sum|w|) + log|det L| - 0.5 * c^T A c
// G storage (shorts): [kstep 33][ct 16][kgrp 4][c 16][e 8]
//   addr = kstep*8192 + (m>>4)*512 + (kloc>>3)*128 + (m&15)*8 + (kloc&7)
// ---------------------------------------------------------------------------
__global__ __launch_bounds__(64) void gmm_prep(
    const float* __restrict__ center,
    const float* __restrict__ L,
    const float* __restrict__ weight,
    short* __restrict__ G,
    float* __restrict__ cst)
{
    const int m = blockIdx.x;
    const int t = threadIdx.x;
    __shared__ float Ls[DIM][DIM + 1];
    __shared__ float As[DIM][DIM + 1];
    __shared__ float Acs[DIM];
    __shared__ float red[DIM];
    __shared__ int pivsh;

    const float* Lm = L + m * DIM * DIM;
    for (int k = t; k < DIM * DIM; k += 64)
        Ls[k >> 5][k & 31] = Lm[k];
    __syncthreads();

    // A = L L^T
    for (int idx = t; idx < DIM * DIM; idx += 64) {
        const int j = idx >> 5, l = idx & 31;
        float a = 0.f;
        for (int d = 0; d < DIM; ++d) a = fmaf(Ls[j][d], Ls[l][d], a);
        As[j][l] = a;
    }
    __syncthreads();

    // E = A - I -> G (bf16, frag order)
    const int mt = m >> 4, ml = m & 15;
    for (int idx = t; idx < DIM * DIM; idx += 64) {
        const int j = idx >> 5, l = idx & 31;
        const float e = As[j][l] - (j == l ? 1.f : 0.f);
        G[j * 8192 + mt * 512 + (l >> 3) * 128 + ml * 8 + (l & 7)] = (short)f2bf(e);
    }
    // Ac and the linear row
    if (t < DIM) {
        float a = 0.f;
        for (int l = 0; l < DIM; ++l) a = fmaf(As[t][l], center[m * DIM + l], a);
        Acs[t] = a;
        G[32 * 8192 + mt * 512 + (t >> 3) * 128 + ml * 8 + (t & 7)] = (short)f2bf(-2.f * a);
        red[t] = a * center[m * DIM + t];
    }
    __syncthreads();

    // Gaussian elimination with partial pivoting on Ls -> log|det L|
    float logdet = 0.f;
    for (int k = 0; k < DIM; ++k) {
        if (t == 0) {
            int piv = k;
            float best = fabsf(Ls[k][k]);
            for (int r = k + 1; r < DIM; ++r) {
                const float v = fabsf(Ls[r][k]);
                if (v > best) { best = v; piv = r; }
            }
            pivsh = piv;
        }
        __syncthreads();
        const int piv = pivsh;
        if (piv != k && t < DIM) {
            const float tmp = Ls[k][t]; Ls[k][t] = Ls[piv][t]; Ls[piv][t] = tmp;
        }
        __syncthreads();
        const float pv = Ls[k][k];
        logdet += logf(fabsf(pv));
        if (t > k && t < DIM) {
            const float f = Ls[t][k] / pv;
            for (int j = k; j < DIM; ++j) Ls[t][j] -= f * Ls[k][j];
        }
        __syncthreads();
    }

    if (t == 0) {
        float wsum = 0.f;
        for (int j = 0; j < MCL; ++j) wsum += fabsf(weight[j]);
        float t3 = 0.f;
        for (int j = 0; j < DIM; ++j) t3 += red[j];
        cst[m] = logf(fabsf(weight[m])) - logf(wsum) + logdet - 0.5f * t3;
    }
}

// ---------------------------------------------------------------------------
// main MFMA kernel: block = 256 points x 256 clusters, K = 33*32.
// A-slices (xx) generated on the fly into LDS; B-slices (G) staged from ws.
// Both LDS tiles stored in exact fragment order: [tile][kgrp(=lane>>4)][r/c(=lane&15)][e*2B]
// so every ds_read/ds_write is lane-contiguous (conflict-free).
// ---------------------------------------------------------------------------
__global__ __launch_bounds__(THREADS, 2) void gmm_mfma(
    const float* __restrict__ X,
    const short* __restrict__ G,
    const float* __restrict__ cstw,
    const float* __restrict__ thr,
    float* __restrict__ out)
{
    __shared__ __attribute__((aligned(16))) short Ab[2][8192];   // 16 KB each
    __shared__ __attribute__((aligned(16))) short Bb[2][8192];
    __shared__ float Xs[BPTS * 33];                              // padded rows
    __shared__ float nrm_s[BPTS];
    __shared__ float cst_s[MCL];
    __shared__ float lse_m[BPTS];
    __shared__ float lse_d[BPTS];

    const int tid  = threadIdx.x;
    const int lane = tid & 63;
    const int w    = tid >> 6;     // wave 0..7
    const int wr   = w & 3;        // row group: 64 points
    const int wc   = w >> 2;       // col group: 128 clusters
    const int P0   = blockIdx.x * BPTS;

    // ---- stage X (f32, padded), keep this thread's 16 x-values in regs
    const int p  = tid >> 1;       // 0..255
    const int hf = tid & 1;        // which 16-K half
    float xr[16];
    {
        const float4* Xg = reinterpret_cast<const float4*>(X + (size_t)(P0 + p) * DIM + hf * 16);
        #pragma unroll
        for (int q = 0; q < 4; ++q) {
            const float4 v = Xg[q];
            const int kb = hf * 16 + 4 * q;
            xr[4 * q + 0] = v.x; xr[4 * q + 1] = v.y;
            xr[4 * q + 2] = v.z; xr[4 * q + 3] = v.w;
            Xs[p * 33 + kb + 0] = v.x; Xs[p * 33 + kb + 1] = v.y;
            Xs[p * 33 + kb + 2] = v.z; Xs[p * 33 + kb + 3] = v.w;
        }
        float part = 0.f;
        #pragma unroll
        for (int e = 0; e < 16; ++e) part = fmaf(xr[e], xr[e], part);
        part += __shfl_xor(part, 1, 64);
        if (!hf) nrm_s[p] = part;
        if (tid < MCL) cst_s[tid] = cstw[tid];
    }
    __syncthreads();

    const int tile = p >> 4, r = p & 15;
    short* const aslot0 = &Ab[0][tile * 512 + (hf * 2) * 128 + r * 8];
    short* const aslot1 = &Ab[1][tile * 512 + (hf * 2) * 128 + r * 8];

    // ---- prologue: fill slice 0
    {
        const s8v g0 = *(const s8v*)(G + 0 * 8192 + w * 1024 + lane * 8);
        const s8v g1 = *(const s8v*)(G + 0 * 8192 + w * 1024 + 512 + lane * 8);
        const float xs = Xs[p * 33 + 0];
        unsigned short h[16];
        #pragma unroll
        for (int e = 0; e < 16; ++e) h[e] = f2bf(xs * xr[e]);
        s8v v0, v1;
        #pragma unroll
        for (int e = 0; e < 8; ++e) { v0[e] = (short)h[e]; v1[e] = (short)h[e + 8]; }
        *(s8v*)aslot0 = v0;
        *(s8v*)(aslot0 + 128) = v1;
        *(s8v*)&Bb[0][w * 1024 + lane * 8] = g0;
        *(s8v*)&Bb[0][w * 1024 + 512 + lane * 8] = g1;
    }
    __syncthreads();

    f32x4 acc[4][8] = {};

    for (int s = 0; s < KSTEPS; ++s) {
        const int cur = s & 1;
        // ---- MFMA phase on cur
        {
            s8v af[4], bf[8];
            #pragma unroll
            for (int i = 0; i < 4; ++i)
                af[i] = *(const s8v*)&Ab[cur][(wr * 4 + i) * 512 + lane * 8];
            #pragma unroll
            for (int j = 0; j < 8; ++j)
                bf[j] = *(const s8v*)&Bb[cur][(wc * 8 + j) * 512 + lane * 8];
            #pragma unroll
            for (int i = 0; i < 4; ++i)
                #pragma unroll
                for (int j = 0; j < 8; ++j)
                    acc[i][j] = __builtin_amdgcn_mfma_f32_16x16x32_bf16(
                        af[i], bf[j], acc[i][j], 0, 0, 0);
        }
        __syncthreads();   // everyone done reading cur (and prior nxt)
        if (s < KSTEPS - 1) {
            const int sn = s + 1, nxt = cur ^ 1;
            // issue global loads first; xx VALU hides their latency
            const s8v g0 = *(const s8v*)(G + sn * 8192 + w * 1024 + lane * 8);
            const s8v g1 = *(const s8v*)(G + sn * 8192 + w * 1024 + 512 + lane * 8);
            const float xs = (sn < 32) ? Xs[p * 33 + sn] : 1.0f;
            unsigned short h[16];
            #pragma unroll
            for (int e = 0; e < 16; ++e) h[e] = f2bf(xs * xr[e]);
            s8v v0, v1;
            #pragma unroll
            for (int e = 0; e < 8; ++e) { v0[e] = (short)h[e]; v1[e] = (short)h[e + 8]; }
            short* const adst = nxt ? aslot1 : aslot0;
            *(s8v*)adst = v0;
            *(s8v*)(adst + 128) = v1;
            *(s8v*)&Bb[nxt][w * 1024 + lane * 8] = g0;
            *(s8v*)&Bb[nxt][w * 1024 + 512 + lane * 8] = g1;
        }
        __syncthreads();   // writes to nxt complete
    }

    // ---- epilogue: two-pass weighted LSE over this wave's 128 clusters
    float cstr[8];
    #pragma unroll
    for (int j = 0; j < 8; ++j)
        cstr[j] = cst_s[wc * 128 + j * 16 + (lane & 15)];

    float mx[16], sm[16];
    #pragma unroll
    for (int i = 0; i < 4; ++i)
        #pragma unroll
        for (int rg = 0; rg < 4; ++rg) {
            const int sl = i * 4 + rg;
            float m_ = -1e30f;
            #pragma unroll
            for (int j = 0; j < 8; ++j)
                m_ = fmaxf(m_, fmaf(acc[i][j][rg], -0.5f, cstr[j]));
            float s_ = 0.f;
            #pragma unroll
            for (int j = 0; j < 8; ++j)
                s_ += __expf(fmaf(acc[i][j][rg], -0.5f, cstr[j]) - m_);
            mx[sl] = m_; sm[sl] = s_;
        }

    // butterfly merge over the 16 col-lanes
    #pragma unroll
    for (int d = 1; d < 16; d <<= 1) {
        #pragma unroll
        for (int sl = 0; sl < 16; ++sl) {
            const float pm = __shfl_xor(mx[sl], d, 64);
            const float ps = __shfl_xor(sm[sl], d, 64);
            const float nm = fmaxf(mx[sl], pm);
            sm[sl] = sm[sl] * __expf(mx[sl] - nm) + ps * __expf(pm - nm);
            mx[sl] = nm;
        }
    }

    // cross col-group merge via LDS
    if (wc == 0 && (lane & 15) == 0) {
        const int hi = lane >> 4;
        #pragma unroll
        for (int i = 0; i < 4; ++i)
            #pragma unroll
            for (int rg = 0; rg < 4; ++rg) {
                const int p2 = wr * 64 + i * 16 + hi * 4 + rg;
                lse_m[p2] = mx[i * 4 + rg];
                lse_d[p2] = sm[i * 4 + rg];
            }
    }
    __syncthreads();
    if (wc == 1 && (lane & 15) == 0) {
        const float thrv = thr[0];
        const int hi = lane >> 4;
        #pragma unroll
        for (int i = 0; i < 4; ++i)
            #pragma unroll
            for (int rg = 0; rg < 4; ++rg) {
                const int sl = i * 4 + rg;
                const int p2 = wr * 64 + i * 16 + hi * 4 + rg;
                const float om = lse_m[p2], os = lse_d[p2];
                const float nm = fmaxf(mx[sl], om);
                const float ss = sm[sl] * __expf(mx[sl] - nm) + os * __expf(om - nm);
                out[P0 + p2] = nm + __logf(ss) - 0.5f * nrm_s[p2] - thrv;
            }
    }
}

extern "C" void kernel_launch(void* const* d_in, const int* in_sizes, int n_in,
                              void* d_out, int out_size, void* d_ws, size_t ws_size,
                              hipStream_t stream)
{
    const float* X      = (const float*)d_in[0];
    const float* center = (const float*)d_in[1];
    const float* L      = (const float*)d_in[2];
    const float* weight = (const float*)d_in[3];
    const float* thr    = (const float*)d_in[4];
    float* out = (float*)d_out;

    // ws layout: cst [256] f32 | G [33*8192] bf16-as-short (~542 KB total)
    float* cst = (float*)d_ws;
    short* G   = (short*)((char*)d_ws + 1024);

    gmm_prep<<<MCL, 64, 0, stream>>>(center, L, weight, G, cst);
    gmm_mfma<<<NPTS / BPTS, THREADS, 0, stream>>>(X, G, cst, thr, out);
}